// Round 10
// baseline (1956.219 us; speedup 1.0000x reference)
//
#include <hip/hip_runtime.h>

#define NN 50000
#define NE 800000
#define DIN 32
#define DD 96
#define NL 4
#define NCLS 10
#define EPSF 1e-6f

typedef unsigned short u16;
typedef unsigned int u32;

typedef __bf16 bf16x8 __attribute__((ext_vector_type(8)));
typedef float f32x4 __attribute__((ext_vector_type(4)));

static __device__ __forceinline__ float bf2f(u16 u) {
    return __uint_as_float(((u32)u) << 16);
}
static __device__ __forceinline__ u16 f2bf(float f) {
    u32 x = __float_as_uint(f);
    x += 0x7FFFu + ((x >> 16) & 1u);   // round-to-nearest-even
    return (u16)(x >> 16);
}
static __device__ __forceinline__ u32 pk2(float a, float b) {
    return (u32)f2bf(a) | ((u32)f2bf(b) << 16);
}
static __device__ __forceinline__ float unlo(u32 u) { return __uint_as_float(u << 16); }
static __device__ __forceinline__ float unhi(u32 u) { return __uint_as_float(u & 0xFFFF0000u); }

__global__ void k_zero_i(int* __restrict__ p, int n) {
    int i = blockIdx.x * blockDim.x + threadIdx.x;
    if (i < n) p[i] = 0;
}

__global__ void k_hist(const int* __restrict__ dst, int* __restrict__ counts) {
    int i = blockIdx.x * blockDim.x + threadIdx.x;
    if (i < NE) atomicAdd(&counts[dst[i]], 1);
}

// single-block exclusive scan over n counts -> row_ptr[0..n], cursor copy.
__global__ __launch_bounds__(1024) void k_scan(const int* __restrict__ counts,
                                               int* __restrict__ row_ptr,
                                               int* __restrict__ cursor, int n) {
    __shared__ int wsum[16];
    __shared__ int carry_s;
    const int tid = threadIdx.x;
    const int lane = tid & 63, wid = tid >> 6;
    if (tid == 0) carry_s = 0;
    __syncthreads();
    for (int base = 0; base < n; base += 1024) {
        int i = base + tid;
        int v = (i < n) ? counts[i] : 0;
        int x = v;
#pragma unroll
        for (int off = 1; off < 64; off <<= 1) {
            int t = __shfl_up(x, (unsigned)off, 64);
            if (lane >= off) x += t;
        }
        if (lane == 63) wsum[wid] = x;
        __syncthreads();
        if (wid == 0 && lane < 16) {
            int s = wsum[lane];
#pragma unroll
            for (int off = 1; off < 16; off <<= 1) {
                int t = __shfl_up(s, (unsigned)off, 16);
                if (lane >= off) s += t;
            }
            wsum[lane] = s;
        }
        __syncthreads();
        int wbase = (wid > 0) ? wsum[wid - 1] : 0;
        int carry = carry_s;
        int excl = carry + wbase + x - v;
        if (i < n) { row_ptr[i] = excl; cursor[i] = excl; }
        __syncthreads();
        if (tid == 0) carry_s = carry + wsum[15];
        __syncthreads();
    }
    if (tid == 0) row_ptr[n] = carry_s;
}

__global__ void k_scatter(const int* __restrict__ src, const int* __restrict__ dst,
                          int* __restrict__ cursor, int* __restrict__ eperm,
                          int* __restrict__ srcp) {
    int i = blockIdx.x * blockDim.x + threadIdx.x;
    if (i >= NE) return;
    int pos = atomicAdd(&cursor[dst[i]], 1);
    eperm[pos] = i;
    srcp[pos] = src[i];
}

// Pack all 4 layers' Cw into MFMA B-fragment order (bf16):
// cwf[l][tile][c][lane][j] = bf16(Cw[l][k=c*32+(lane>>4)*8+j][n=tile*16+(lane&15)])
__global__ void k_packCw(const float* __restrict__ Cw_all, u16* __restrict__ cwf) {
    int q = blockIdx.x * blockDim.x + threadIdx.x;   // fragment index
    if (q >= NL * 6 * 3 * 64) return;
    int l = q / (6 * 3 * 64);
    int rem = q - l * (6 * 3 * 64);
    int tile = rem / (3 * 64);
    int rem2 = rem - tile * (3 * 64);
    int c = rem2 >> 6, lane = rem2 & 63;
    const float* Cw = Cw_all + (long)l * DD * DD;
    int n = tile * 16 + (lane & 15);
    int k0 = c * 32 + (lane >> 4) * 8;
    u16 w[8];
#pragma unroll
    for (int j = 0; j < 8; ++j) w[j] = f2bf(Cw[(k0 + j) * DD + n]);
    *(uint4*)&cwf[(long)q * 8] = *(uint4*)w;
}

// Pack a [32,96] projection W into B-fragment order (6 tiles x 64 lanes x 8)
__global__ void k_packW32(const float* __restrict__ W, u16* __restrict__ wf) {
    int q = blockIdx.x * blockDim.x + threadIdx.x;
    if (q >= 6 * 64) return;
    int tile = q >> 6, lane = q & 63;
    int n = tile * 16 + (lane & 15);
    int k0 = (lane >> 4) * 8;
    u16 w[8];
#pragma unroll
    for (int j = 0; j < 8; ++j) w[j] = f2bf(W[(k0 + j) * DD + n]);
    *(uint4*)&wf[q * 8] = *(uint4*)w;
}

// Barrier-free MFMA input projection: one wave per 16-row tile, grid-stride.
// Y[row,:] = X[permrow,:32] @ W + B. K=32 = exactly one mfma_16x16x32 step.
// A-frag loaded straight from global (32B/lane); W-frags register-resident.
template <bool BFOUT, bool PERM>
__global__ __launch_bounds__(256) void k_proj_m(const float* __restrict__ X,
                                                const u16* __restrict__ wf,
                                                const float* __restrict__ B,
                                                void* __restrict__ Y,
                                                const int* __restrict__ eperm,
                                                int ntiles) {
    const int lane = threadIdx.x & 63;
    const int gw = (blockIdx.x * blockDim.x + threadIdx.x) >> 6;
    const int nw = (gridDim.x * blockDim.x) >> 6;
    const int lm = lane & 15, quad = lane >> 4;

    bf16x8 bfr[6];
    float bias[6];
#pragma unroll
    for (int t = 0; t < 6; ++t) {
        bfr[t] = *(const bf16x8*)&wf[(t * 64 + lane) * 8];
        bias[t] = B[t * 16 + lm];
    }

    for (int tile = gw; tile < ntiles; tile += nw) {
        const int row = tile * 16 + lm;
        const long srow = PERM ? (long)eperm[row] : (long)row;
        float4 x0 = *(const float4*)&X[srow * DIN + quad * 8];
        float4 x1 = *(const float4*)&X[srow * DIN + quad * 8 + 4];
        u32 ap[4] = {pk2(x0.x, x0.y), pk2(x0.z, x0.w), pk2(x1.x, x1.y), pk2(x1.z, x1.w)};
        bf16x8 af = *(bf16x8*)ap;
        f32x4 acc[6];
#pragma unroll
        for (int t = 0; t < 6; ++t) {
            acc[t] = (f32x4){0.f, 0.f, 0.f, 0.f};
            acc[t] = __builtin_amdgcn_mfma_f32_16x16x32_bf16(af, bfr[t], acc[t], 0, 0, 0);
        }
        // C layout: row = tile*16 + quad*4 + r, col = t*16 + lm
        const long rbase = (long)tile * 16 + quad * 4;
#pragma unroll
        for (int t = 0; t < 6; ++t) {
            const int j = t * 16 + lm;
#pragma unroll
            for (int r = 0; r < 4; ++r) {
                float v = acc[t][r] + bias[t];
                if (BFOUT) ((u16*)Y)[(rbase + r) * DD + j] = f2bf(v);
                else       ((float*)Y)[(rbase + r) * DD + j] = v;
            }
        }
    }
}

// Fused 4-way node GEMM (VALU path).
__global__ __launch_bounds__(192) void k_gemm4(const float* __restrict__ X,
                                               const float* __restrict__ W0, const float* __restrict__ b0,
                                               const float* __restrict__ W1, const float* __restrict__ b1,
                                               const float* __restrict__ W2, const float* __restrict__ b2,
                                               const float* __restrict__ W3, const float* __restrict__ b3,
                                               float* __restrict__ Y0, u16* __restrict__ Y1,
                                               u16* __restrict__ Y2, u16* __restrict__ Y3,
                                               int nrows) {
    __shared__ u32 wsp[DD * 48];
    __shared__ float xs[32 * 100];
    const int tid = threadIdx.x;
    const int row0 = blockIdx.x * 32;
#pragma unroll
    for (int t = 0; t < 4; ++t) {
        int q = tid + t * 192;
        int r = q / 24, c4 = q - r * 24;
        int row = row0 + r;
        float4 v = make_float4(0.f, 0.f, 0.f, 0.f);
        if (row < nrows) v = *(const float4*)&X[(long)row * DD + c4 * 4];
        *(float4*)&xs[r * 100 + c4 * 4] = v;
    }
    const float* Ws[4] = {W0, W1, W2, W3};
    const float* Bs[4] = {b0, b1, b2, b3};
    const int je = tid % 24, ge = tid / 24;
    const int j0 = je * 4, r0 = ge * 4;
    for (int m = 0; m < 4; ++m) {
        {
            const float4* Wv = (const float4*)Ws[m];
            uint2* wv = (uint2*)wsp;
#pragma unroll
            for (int t = 0; t < 12; ++t) {
                float4 v = Wv[tid + t * 192];
                wv[tid + t * 192] = make_uint2(pk2(v.x, v.y), pk2(v.z, v.w));
            }
        }
        __syncthreads();
        float acc[4][4] = {};
#pragma unroll 4
        for (int k4 = 0; k4 < 24; ++k4) {
            const int kk = k4 * 4;
            float4 a0 = *(const float4*)&xs[(r0 + 0) * 100 + kk];
            float4 a1 = *(const float4*)&xs[(r0 + 1) * 100 + kk];
            float4 a2 = *(const float4*)&xs[(r0 + 2) * 100 + kk];
            float4 a3 = *(const float4*)&xs[(r0 + 3) * 100 + kk];
            uint2 u0 = *(const uint2*)&wsp[(kk + 0) * 48 + je * 2];
            uint2 u1 = *(const uint2*)&wsp[(kk + 1) * 48 + je * 2];
            uint2 u2 = *(const uint2*)&wsp[(kk + 2) * 48 + je * 2];
            uint2 u3 = *(const uint2*)&wsp[(kk + 3) * 48 + je * 2];
            float4 w0 = make_float4(unlo(u0.x), unhi(u0.x), unlo(u0.y), unhi(u0.y));
            float4 w1 = make_float4(unlo(u1.x), unhi(u1.x), unlo(u1.y), unhi(u1.y));
            float4 w2 = make_float4(unlo(u2.x), unhi(u2.x), unlo(u2.y), unhi(u2.y));
            float4 w3 = make_float4(unlo(u3.x), unhi(u3.x), unlo(u3.y), unhi(u3.y));
#define ROWFMA(i, a)                                                                  \
    acc[i][0] = fmaf(a.x, w0.x, fmaf(a.y, w1.x, fmaf(a.z, w2.x, fmaf(a.w, w3.x, acc[i][0])))); \
    acc[i][1] = fmaf(a.x, w0.y, fmaf(a.y, w1.y, fmaf(a.z, w2.y, fmaf(a.w, w3.y, acc[i][1])))); \
    acc[i][2] = fmaf(a.x, w0.z, fmaf(a.y, w1.z, fmaf(a.z, w2.z, fmaf(a.w, w3.z, acc[i][2])))); \
    acc[i][3] = fmaf(a.x, w0.w, fmaf(a.y, w1.w, fmaf(a.z, w2.w, fmaf(a.w, w3.w, acc[i][3]))));
            ROWFMA(0, a0) ROWFMA(1, a1) ROWFMA(2, a2) ROWFMA(3, a3)
#undef ROWFMA
        }
        const float* Bm = Bs[m];
        const float bb0 = Bm[j0], bb1 = Bm[j0 + 1], bb2 = Bm[j0 + 2], bb3 = Bm[j0 + 3];
#pragma unroll
        for (int i = 0; i < 4; ++i) {
            int row = row0 + r0 + i;
            if (row >= nrows) continue;
            float v0 = acc[i][0] + bb0, v1 = acc[i][1] + bb1;
            float v2 = acc[i][2] + bb2, v3 = acc[i][3] + bb3;
            if (m == 0) {
                *(float4*)&Y0[(long)row * DD + j0] = make_float4(v0, v1, v2, v3);
            } else {
                u16* Yp = (m == 1) ? Y1 : ((m == 2) ? Y2 : Y3);
                *(uint2*)&Yp[(long)row * DD + j0] = make_uint2(pk2(v0, v1), pk2(v2, v3));
            }
        }
        __syncthreads();
    }
}

// Persistent per-destination-node fused edge+aggregate kernel — MFMA,
// register-resident B-fragments, grid-stride over nodes.
__global__ __launch_bounds__(192) void k_node_edge(u16* ebuf,
                                                   const u16* __restrict__ cwf,  // [6][3][64][8]
                                                   const float* __restrict__ Cb,
                                                   const u16* __restrict__ Dh,
                                                   const u16* __restrict__ Eh,
                                                   const u16* __restrict__ Bh,
                                                   const int* __restrict__ srcp,
                                                   const int* __restrict__ row_ptr,
                                                   const float* __restrict__ Ah,
                                                   float* __restrict__ hbuf) {
#define LSTR 104
    __shared__ u16 atile[16 * LSTR];  // 3.3 KB  e-tile bf16 [m][k]
    __shared__ float snum[DD], sden[DD];
    __shared__ int ssrc[16];
    const int tid = threadIdx.x;
    const int lane = tid & 63;
    const int wv = tid >> 6;          // wave 0..2 -> col tiles {2wv, 2wv+1}
    const int lm = lane & 15;
    const int quad = lane >> 4;
    const int srow = tid / 12, sc8 = tid - srow * 12;

    // B-fragments + per-lane column constants: hoisted for the whole block
    bf16x8 bfrag[2][3];
#pragma unroll
    for (int t = 0; t < 2; ++t)
#pragma unroll
        for (int c = 0; c < 3; ++c)
            bfrag[t][c] = *(const bf16x8*)&cwf[(((long)(2 * wv + t) * 3 + c) * 64 + lane) * 8];
    const int j0c = (2 * wv + 0) * 16 + lm;
    const int j1c = (2 * wv + 1) * 16 + lm;
    const float cb0 = Cb[j0c], cb1 = Cb[j1c];

    for (int n = blockIdx.x; n < NN; n += gridDim.x) {
        const int r0 = row_ptr[n], r1 = row_ptr[n + 1];
        const float eh0 = bf2f(Eh[(long)n * DD + j0c]);
        const float eh1 = bf2f(Eh[(long)n * DD + j1c]);
        float nacc[2] = {0.f, 0.f}, dacc[2] = {0.f, 0.f};

        for (int chunk = r0; chunk < r1; chunk += 16) {
            const int rows = min(16, r1 - chunk);
            if (srow < rows) {   // pad rows stale: their C rows are never read
                uint4 u = *(const uint4*)&ebuf[(long)(chunk + srow) * DD + sc8 * 8];
                *(uint4*)&atile[srow * LSTR + sc8 * 8] = u;
            }
            if (tid < 16) ssrc[tid] = (chunk + tid < r1) ? srcp[chunk + tid] : 0;
            __syncthreads();

            f32x4 acc0 = {0.f, 0.f, 0.f, 0.f}, acc1 = {0.f, 0.f, 0.f, 0.f};
#pragma unroll
            for (int c = 0; c < 3; ++c) {
                bf16x8 a = *(const bf16x8*)&atile[lm * LSTR + c * 32 + quad * 8];
                acc0 = __builtin_amdgcn_mfma_f32_16x16x32_bf16(a, bfrag[0][c], acc0, 0, 0, 0);
                acc1 = __builtin_amdgcn_mfma_f32_16x16x32_bf16(a, bfrag[1][c], acc1, 0, 0, 0);
            }
#pragma unroll
            for (int t = 0; t < 2; ++t) {
                const int j = t ? j1c : j0c;
                const float cbj = t ? cb1 : cb0;
                const float ehj = t ? eh1 : eh0;
#pragma unroll
                for (int r = 0; r < 4; ++r) {
                    const int rl = quad * 4 + r;
                    if (rl < rows) {
                        const int s = ssrc[rl];
                        float dh = bf2f(Dh[(long)s * DD + j]);
                        float bh = bf2f(Bh[(long)s * DD + j]);
                        float en = (t ? acc1[r] : acc0[r]) + cbj + dh + ehj;
                        float sg = 1.f / (1.f + __expf(-en));
                        nacc[t] += bh * sg;
                        dacc[t] += sg;
                        float old = bf2f(atile[rl * LSTR + j]);
                        ebuf[(long)(chunk + rl) * DD + j] = f2bf(old + fmaxf(en, 0.f));
                    }
                }
            }
            __syncthreads();   // atile reused next chunk
        }
        // reduce num/den over quads (butterfly), stash per-col sums
#pragma unroll
        for (int t = 0; t < 2; ++t) {
            float x = nacc[t], y = dacc[t];
            x += __shfl_xor(x, 16); y += __shfl_xor(y, 16);
            x += __shfl_xor(x, 32); y += __shfl_xor(y, 32);
            if (lane < 16) { snum[(2 * wv + t) * 16 + lane] = x; sden[(2 * wv + t) * 16 + lane] = y; }
        }
        __syncthreads();
        if (tid < DD) {
            float val = Ah[(long)n * DD + tid] + snum[tid] / (sden[tid] + EPSF);
            hbuf[(long)n * DD + tid] += fmaxf(val, 0.f);
        }
        __syncthreads();   // snum/atile reuse next node (incl. degree-0 path)
    }
#undef LSTR
}

// small MLP stage, one thread per output element
__global__ void k_mlp(const float* __restrict__ X, const float* __restrict__ W,
                      const float* __restrict__ B, float* __restrict__ Y,
                      int K, int Dout, int act, long total) {
    long idx = (long)blockIdx.x * blockDim.x + threadIdx.x;
    if (idx >= total) return;
    int row = (int)(idx / Dout);
    int j = (int)(idx - (long)row * Dout);
    const float* xr = X + (long)row * K;
    float acc = B[j];
    for (int k = 0; k < K; ++k) acc = fmaf(xr[k], W[k * Dout + j], acc);
    if (act == 1) acc = fmaxf(acc, 0.f);
    else if (act == 2) acc = 1.f / (1.f + __expf(-acc));
    Y[idx] = acc;
}

extern "C" void kernel_launch(void* const* d_in, const int* in_sizes, int n_in,
                              void* d_out, int out_size, void* d_ws, size_t ws_size,
                              hipStream_t stream) {
    const float* h_in = (const float*)d_in[0];
    const float* e_in = (const float*)d_in[1];
    const int* src = (const int*)d_in[2];
    const int* dst = (const int*)d_in[3];
    const float* fp_w = (const float*)d_in[4];
    const float* fp_b = (const float*)d_in[5];
    const float* ep_w = (const float*)d_in[6];
    const float* ep_b = (const float*)d_in[7];
    const float* A_w = (const float*)d_in[8];
    const float* A_b = (const float*)d_in[9];
    const float* B_w = (const float*)d_in[10];
    const float* B_b = (const float*)d_in[11];
    const float* C_w = (const float*)d_in[12];
    const float* C_b = (const float*)d_in[13];
    const float* D_w = (const float*)d_in[14];
    const float* D_b = (const float*)d_in[15];
    const float* E_w = (const float*)d_in[16];
    const float* E_b = (const float*)d_in[17];
    const float* mlp0_w = (const float*)d_in[18];
    const float* mlp0_b = (const float*)d_in[19];
    const float* mlp1_w = (const float*)d_in[20];
    const float* mlp1_b = (const float*)d_in[21];
    const float* mlp2_w = (const float*)d_in[22];
    const float* mlp2_b = (const float*)d_in[23];
    float* out = (float*)d_out;

    const size_t ND = (size_t)NN * DD;
    const size_t ED = (size_t)NE * DD;
    char* w = (char*)d_ws;
    float* hbuf = (float*)w; w += ND * 4;
    float* Ahb  = (float*)w; w += ND * 4;
    u16* Bhb = (u16*)w; w += ND * 2;
    u16* Dhb = (u16*)w; w += ND * 2;
    u16* Ehb = (u16*)w; w += ND * 2;
    u16* ebuf = (u16*)w; w += ED * 2;
    int* counts  = (int*)w; w += (size_t)NN * 4;
    int* row_ptr = (int*)w; w += (size_t)(NN + 1) * 4 + 12;
    int* cursor  = (int*)w; w += (size_t)NN * 4;
    int* eperm   = (int*)w; w += (size_t)NE * 4;
    int* srcp    = (int*)w; w += (size_t)NE * 4;
    u16* cwf     = (u16*)w; w += (size_t)NL * 6 * 3 * 64 * 8 * 2;   // 73.7 KB
    u16* wfp     = (u16*)w; w += (size_t)6 * 64 * 8 * 2;            // 6 KB
    u16* wep     = (u16*)w; w += (size_t)6 * 64 * 8 * 2;            // 6 KB
    size_t need = (size_t)(w - (char*)d_ws);
    if (ws_size < need) return;  // uniform -> graph-safe; fails absmax as diagnostic

    // CSR build (dst-sorted edge permutation) + weight fragment packs
    k_zero_i<<<(NN + 255) / 256, 256, 0, stream>>>(counts, NN);
    k_hist<<<(NE + 255) / 256, 256, 0, stream>>>(dst, counts);
    k_scan<<<1, 1024, 0, stream>>>(counts, row_ptr, cursor, NN);
    k_scatter<<<(NE + 255) / 256, 256, 0, stream>>>(src, dst, cursor, eperm, srcp);
    k_packCw<<<(NL * 6 * 3 * 64 + 255) / 256, 256, 0, stream>>>(C_w, cwf);
    k_packW32<<<2, 256, 0, stream>>>(fp_w, wfp);
    k_packW32<<<2, 256, 0, stream>>>(ep_w, wep);

    // input projections, barrier-free MFMA (edge proj lands in dst-sorted order)
    k_proj_m<false, false><<<256, 256, 0, stream>>>(h_in, wfp, fp_b, hbuf, nullptr, NN / 16);
    k_proj_m<true, true><<<1024, 256, 0, stream>>>(e_in, wep, ep_b, ebuf, eperm, NE / 16);

    const int gN = (NN + 31) / 32;
    for (int l = 0; l < NL; ++l) {
        const float* Aw = A_w + (size_t)l * DD * DD; const float* Ab = A_b + (size_t)l * DD;
        const float* Bw = B_w + (size_t)l * DD * DD; const float* Bb = B_b + (size_t)l * DD;
        const float* Cb = C_b + (size_t)l * DD;
        const float* Dw = D_w + (size_t)l * DD * DD; const float* Db = D_b + (size_t)l * DD;
        const float* Ew = E_w + (size_t)l * DD * DD; const float* Eb = E_b + (size_t)l * DD;
        const u16* cwf_l = cwf + (size_t)l * 6 * 3 * 64 * 8;

        k_gemm4<<<gN, 192, 0, stream>>>(hbuf, Aw, Ab, Bw, Bb, Dw, Db, Ew, Eb,
                                        Ahb, Bhb, Dhb, Ehb, NN);
        k_node_edge<<<2560, 192, 0, stream>>>(ebuf, cwf_l, Cb, Dhb, Ehb, Bhb, srcp, row_ptr,
                                              Ahb, hbuf);
    }

    // MLP readout: 96 -> 48 (relu) -> 24 (relu) -> 10 (sigmoid). Reuse Ahb as temps.
    float* y1 = Ahb;
    float* y2 = Ahb + (size_t)NN * 48;
    long t0 = (long)NN * 48, t1 = (long)NN * 24, t2 = (long)NN * NCLS;
    k_mlp<<<(int)((t0 + 255) / 256), 256, 0, stream>>>(hbuf, mlp0_w, mlp0_b, y1, DD, 48, 1, t0);
    k_mlp<<<(int)((t1 + 255) / 256), 256, 0, stream>>>(y1, mlp1_w, mlp1_b, y2, 48, 24, 1, t1);
    k_mlp<<<(int)((t2 + 255) / 256), 256, 0, stream>>>(y2, mlp2_w, mlp2_b, out, 24, NCLS, 2, t2);
}

// Round 11
// 1475.618 us; speedup vs baseline: 1.3257x; 1.3257x over previous
//
#include <hip/hip_runtime.h>

#define NN 50000
#define NE 800000
#define DIN 32
#define DD 96
#define NL 4
#define NCLS 10
#define EPSF 1e-6f

typedef unsigned short u16;
typedef unsigned int u32;

typedef __bf16 bf16x8 __attribute__((ext_vector_type(8)));
typedef float f32x4 __attribute__((ext_vector_type(4)));

static __device__ __forceinline__ float bf2f(u16 u) {
    return __uint_as_float(((u32)u) << 16);
}
static __device__ __forceinline__ u16 f2bf(float f) {
    u32 x = __float_as_uint(f);
    x += 0x7FFFu + ((x >> 16) & 1u);   // round-to-nearest-even
    return (u16)(x >> 16);
}
static __device__ __forceinline__ u32 pk2(float a, float b) {
    return (u32)f2bf(a) | ((u32)f2bf(b) << 16);
}

__global__ void k_zero_i(int* __restrict__ p, int n) {
    int i = blockIdx.x * blockDim.x + threadIdx.x;
    if (i < n) p[i] = 0;
}

__global__ void k_hist(const int* __restrict__ dst, int* __restrict__ counts) {
    int i = blockIdx.x * blockDim.x + threadIdx.x;
    if (i < NE) atomicAdd(&counts[dst[i]], 1);
}

// single-block exclusive scan over n counts -> row_ptr[0..n], cursor copy.
__global__ __launch_bounds__(1024) void k_scan(const int* __restrict__ counts,
                                               int* __restrict__ row_ptr,
                                               int* __restrict__ cursor, int n) {
    __shared__ int wsum[16];
    __shared__ int carry_s;
    const int tid = threadIdx.x;
    const int lane = tid & 63, wid = tid >> 6;
    if (tid == 0) carry_s = 0;
    __syncthreads();
    for (int base = 0; base < n; base += 1024) {
        int i = base + tid;
        int v = (i < n) ? counts[i] : 0;
        int x = v;
#pragma unroll
        for (int off = 1; off < 64; off <<= 1) {
            int t = __shfl_up(x, (unsigned)off, 64);
            if (lane >= off) x += t;
        }
        if (lane == 63) wsum[wid] = x;
        __syncthreads();
        if (wid == 0 && lane < 16) {
            int s = wsum[lane];
#pragma unroll
            for (int off = 1; off < 16; off <<= 1) {
                int t = __shfl_up(s, (unsigned)off, 16);
                if (lane >= off) s += t;
            }
            wsum[lane] = s;
        }
        __syncthreads();
        int wbase = (wid > 0) ? wsum[wid - 1] : 0;
        int carry = carry_s;
        int excl = carry + wbase + x - v;
        if (i < n) { row_ptr[i] = excl; cursor[i] = excl; }
        __syncthreads();
        if (tid == 0) carry_s = carry + wsum[15];
        __syncthreads();
    }
    if (tid == 0) row_ptr[n] = carry_s;
}

__global__ void k_scatter(const int* __restrict__ src, const int* __restrict__ dst,
                          int* __restrict__ cursor, int* __restrict__ eperm,
                          int* __restrict__ srcp) {
    int i = blockIdx.x * blockDim.x + threadIdx.x;
    if (i >= NE) return;
    int pos = atomicAdd(&cursor[dst[i]], 1);
    eperm[pos] = i;
    srcp[pos] = src[i];
}

// Pack a [NL][96][96] weight tensor into MFMA B-fragment order (bf16):
// wf[l][tile][c][lane][j] = bf16(W[l][k=c*32+(lane>>4)*8+j][n=tile*16+(lane&15)])
__global__ void k_packCw(const float* __restrict__ W_all, u16* __restrict__ wf) {
    int q = blockIdx.x * blockDim.x + threadIdx.x;   // fragment index
    if (q >= NL * 6 * 3 * 64) return;
    int l = q / (6 * 3 * 64);
    int rem = q - l * (6 * 3 * 64);
    int tile = rem / (3 * 64);
    int rem2 = rem - tile * (3 * 64);
    int c = rem2 >> 6, lane = rem2 & 63;
    const float* W = W_all + (long)l * DD * DD;
    int n = tile * 16 + (lane & 15);
    int k0 = c * 32 + (lane >> 4) * 8;
    u16 w[8];
#pragma unroll
    for (int j = 0; j < 8; ++j) w[j] = f2bf(W[(k0 + j) * DD + n]);
    *(uint4*)&wf[(long)q * 8] = *(uint4*)w;
}

// Pack a [32,96] projection W into B-fragment order (6 tiles x 64 lanes x 8)
__global__ void k_packW32(const float* __restrict__ W, u16* __restrict__ wf) {
    int q = blockIdx.x * blockDim.x + threadIdx.x;
    if (q >= 6 * 64) return;
    int tile = q >> 6, lane = q & 63;
    int n = tile * 16 + (lane & 15);
    int k0 = (lane >> 4) * 8;
    u16 w[8];
#pragma unroll
    for (int j = 0; j < 8; ++j) w[j] = f2bf(W[(k0 + j) * DD + n]);
    *(uint4*)&wf[q * 8] = *(uint4*)w;
}

// Barrier-free MFMA input projection: one wave per 16-row tile, grid-stride.
template <bool BFOUT, bool PERM>
__global__ __launch_bounds__(256) void k_proj_m(const float* __restrict__ X,
                                                const u16* __restrict__ wf,
                                                const float* __restrict__ B,
                                                void* __restrict__ Y,
                                                const int* __restrict__ eperm,
                                                int ntiles) {
    const int lane = threadIdx.x & 63;
    const int gw = (blockIdx.x * blockDim.x + threadIdx.x) >> 6;
    const int nw = (gridDim.x * blockDim.x) >> 6;
    const int lm = lane & 15, quad = lane >> 4;

    bf16x8 bfr[6];
    float bias[6];
#pragma unroll
    for (int t = 0; t < 6; ++t) {
        bfr[t] = *(const bf16x8*)&wf[(t * 64 + lane) * 8];
        bias[t] = B[t * 16 + lm];
    }

    for (int tile = gw; tile < ntiles; tile += nw) {
        const int row = tile * 16 + lm;
        const long srow = PERM ? (long)eperm[row] : (long)row;
        float4 x0 = *(const float4*)&X[srow * DIN + quad * 8];
        float4 x1 = *(const float4*)&X[srow * DIN + quad * 8 + 4];
        u32 ap[4] = {pk2(x0.x, x0.y), pk2(x0.z, x0.w), pk2(x1.x, x1.y), pk2(x1.z, x1.w)};
        bf16x8 af = *(bf16x8*)ap;
        f32x4 acc[6];
#pragma unroll
        for (int t = 0; t < 6; ++t) {
            acc[t] = (f32x4){0.f, 0.f, 0.f, 0.f};
            acc[t] = __builtin_amdgcn_mfma_f32_16x16x32_bf16(af, bfr[t], acc[t], 0, 0, 0);
        }
        const long rbase = (long)tile * 16 + quad * 4;
#pragma unroll
        for (int t = 0; t < 6; ++t) {
            const int j = t * 16 + lm;
#pragma unroll
            for (int r = 0; r < 4; ++r) {
                float v = acc[t][r] + bias[t];
                if (BFOUT) ((u16*)Y)[(rbase + r) * DD + j] = f2bf(v);
                else       ((float*)Y)[(rbase + r) * DD + j] = v;
            }
        }
    }
}

// Barrier-free MFMA 4-way node GEMM: block = 4 waves, wave w handles matrix w
// for the block's tile (shared X rows -> L1 hits). Grid-stride over tiles.
// NN = 16*3125 exactly -> no row guards.
__global__ __launch_bounds__(256) void k_gemm4m(const float* __restrict__ X,
                                                const u16* __restrict__ awf, const float* __restrict__ ab,
                                                const u16* __restrict__ bwf, const float* __restrict__ bb,
                                                const u16* __restrict__ dwf, const float* __restrict__ db,
                                                const u16* __restrict__ ewf, const float* __restrict__ eb,
                                                float* __restrict__ Y0, u16* __restrict__ Y1,
                                                u16* __restrict__ Y2, u16* __restrict__ Y3,
                                                int ntiles) {
    const int lane = threadIdx.x & 63;
    const int w = threadIdx.x >> 6;   // matrix 0..3
    const int lm = lane & 15, quad = lane >> 4;
    const u16* wf = (w == 0) ? awf : (w == 1) ? bwf : (w == 2) ? dwf : ewf;
    const float* bp = (w == 0) ? ab : (w == 1) ? bb : (w == 2) ? db : eb;

    bf16x8 bfr[6][3];
    float bias[6];
#pragma unroll
    for (int t = 0; t < 6; ++t) {
#pragma unroll
        for (int c = 0; c < 3; ++c)
            bfr[t][c] = *(const bf16x8*)&wf[((t * 3 + c) * 64 + lane) * 8];
        bias[t] = bp[t * 16 + lm];
    }

    for (int tile = blockIdx.x; tile < ntiles; tile += gridDim.x) {
        const float* xr = X + (long)(tile * 16 + lm) * DD;
        bf16x8 a[3];
#pragma unroll
        for (int c = 0; c < 3; ++c) {
            float4 x0 = *(const float4*)&xr[c * 32 + quad * 8];
            float4 x1 = *(const float4*)&xr[c * 32 + quad * 8 + 4];
            u32 ap[4] = {pk2(x0.x, x0.y), pk2(x0.z, x0.w), pk2(x1.x, x1.y), pk2(x1.z, x1.w)};
            a[c] = *(bf16x8*)ap;
        }
        f32x4 acc[6];
#pragma unroll
        for (int t = 0; t < 6; ++t) {
            acc[t] = (f32x4){0.f, 0.f, 0.f, 0.f};
#pragma unroll
            for (int c = 0; c < 3; ++c)
                acc[t] = __builtin_amdgcn_mfma_f32_16x16x32_bf16(a[c], bfr[t][c], acc[t], 0, 0, 0);
        }
        const long rbase = (long)tile * 16 + quad * 4;
#pragma unroll
        for (int t = 0; t < 6; ++t) {
            const int j = t * 16 + lm;
#pragma unroll
            for (int r = 0; r < 4; ++r) {
                float v = acc[t][r] + bias[t];
                if (w == 0) {
                    Y0[(rbase + r) * DD + j] = v;
                } else {
                    u16* Yp = (w == 1) ? Y1 : (w == 2) ? Y2 : Y3;
                    Yp[(rbase + r) * DD + j] = f2bf(v);
                }
            }
        }
    }
}

// Barrier-free, LDS-free fused edge+aggregate: ONE WAVE PER NODE (grid-stride).
// A-frags loaded straight from global (wave reads 16 rows x 64B segments);
// 18 register B-frags (pre-packed Cw); epilogue in C layout; num/den in regs
// across chunks; quad-butterfly reduce; quad-0 lanes write h.
__global__ __launch_bounds__(256) void k_node_edge_w(u16* ebuf,
                                                     const u16* __restrict__ cwf,  // [6][3][64][8]
                                                     const float* __restrict__ Cb,
                                                     const u16* __restrict__ Dh,
                                                     const u16* __restrict__ Eh,
                                                     const u16* __restrict__ Bh,
                                                     const int* __restrict__ srcp,
                                                     const int* __restrict__ row_ptr,
                                                     const float* __restrict__ Ah,
                                                     float* __restrict__ hbuf) {
    const int lane = threadIdx.x & 63;
    const int gw = (blockIdx.x * blockDim.x + threadIdx.x) >> 6;
    const int nw = (gridDim.x * blockDim.x) >> 6;
    const int lm = lane & 15, quad = lane >> 4;

    bf16x8 bfrag[6][3];
    float cb[6];
#pragma unroll
    for (int t = 0; t < 6; ++t) {
#pragma unroll
        for (int c = 0; c < 3; ++c)
            bfrag[t][c] = *(const bf16x8*)&cwf[((t * 3 + c) * 64 + lane) * 8];
        cb[t] = Cb[t * 16 + lm];
    }

    for (int n = gw; n < NN; n += nw) {
        const int r0 = row_ptr[n], r1 = row_ptr[n + 1];
        float eh[6];
#pragma unroll
        for (int t = 0; t < 6; ++t) eh[t] = bf2f(Eh[(long)n * DD + t * 16 + lm]);
        float nacc[6] = {0.f, 0.f, 0.f, 0.f, 0.f, 0.f};
        float dacc[6] = {0.f, 0.f, 0.f, 0.f, 0.f, 0.f};

        for (int chunk = r0; chunk < r1; chunk += 16) {
            const int rows = r1 - chunk < 16 ? r1 - chunk : 16;
            // A-frags direct from global: row = chunk+lm (clamped), k = c*32+quad*8
            const long arow = chunk + (lm < rows ? lm : 0);
            bf16x8 a[3];
#pragma unroll
            for (int c = 0; c < 3; ++c)
                a[c] = *(const bf16x8*)&ebuf[arow * DD + c * 32 + quad * 8];
            // src ids for this quad's 4 rows (broadcast across lm)
            int sr[4];
#pragma unroll
            for (int r = 0; r < 4; ++r) {
                int rl = quad * 4 + r;
                sr[r] = (chunk + rl < r1) ? srcp[chunk + rl] : 0;
            }
            f32x4 acc[6];
#pragma unroll
            for (int t = 0; t < 6; ++t) {
                acc[t] = (f32x4){0.f, 0.f, 0.f, 0.f};
#pragma unroll
                for (int c = 0; c < 3; ++c)
                    acc[t] = __builtin_amdgcn_mfma_f32_16x16x32_bf16(a[c], bfrag[t][c], acc[t], 0, 0, 0);
            }
            // epilogue: C layout row = quad*4+r, col = t*16+lm
#pragma unroll
            for (int r = 0; r < 4; ++r) {
                const int rl = quad * 4 + r;
                if (rl < rows) {
                    const long s = sr[r];
                    const long eg = (long)(chunk + rl) * DD;
#pragma unroll
                    for (int t = 0; t < 6; ++t) {
                        const int j = t * 16 + lm;
                        float dh = bf2f(Dh[s * DD + j]);
                        float bh = bf2f(Bh[s * DD + j]);
                        float en = acc[t][r] + cb[t] + dh + eh[t];
                        float sg = 1.f / (1.f + __expf(-en));
                        nacc[t] += bh * sg;
                        dacc[t] += sg;
                        float old = bf2f(ebuf[eg + j]);
                        ebuf[eg + j] = f2bf(old + fmaxf(en, 0.f));
                    }
                }
            }
        }
        // reduce over quads (butterfly across lane bits 4-5)
#pragma unroll
        for (int t = 0; t < 6; ++t) {
            float x = nacc[t], y = dacc[t];
            x += __shfl_xor(x, 16); y += __shfl_xor(y, 16);
            x += __shfl_xor(x, 32); y += __shfl_xor(y, 32);
            nacc[t] = x; dacc[t] = y;
        }
        if (quad == 0) {
#pragma unroll
            for (int t = 0; t < 6; ++t) {
                const int j = t * 16 + lm;
                float val = Ah[(long)n * DD + j] + nacc[t] / (dacc[t] + EPSF);
                hbuf[(long)n * DD + j] += fmaxf(val, 0.f);
            }
        }
    }
}

// small MLP stage, one thread per output element
__global__ void k_mlp(const float* __restrict__ X, const float* __restrict__ W,
                      const float* __restrict__ B, float* __restrict__ Y,
                      int K, int Dout, int act, long total) {
    long idx = (long)blockIdx.x * blockDim.x + threadIdx.x;
    if (idx >= total) return;
    int row = (int)(idx / Dout);
    int j = (int)(idx - (long)row * Dout);
    const float* xr = X + (long)row * K;
    float acc = B[j];
    for (int k = 0; k < K; ++k) acc = fmaf(xr[k], W[k * Dout + j], acc);
    if (act == 1) acc = fmaxf(acc, 0.f);
    else if (act == 2) acc = 1.f / (1.f + __expf(-acc));
    Y[idx] = acc;
}

extern "C" void kernel_launch(void* const* d_in, const int* in_sizes, int n_in,
                              void* d_out, int out_size, void* d_ws, size_t ws_size,
                              hipStream_t stream) {
    const float* h_in = (const float*)d_in[0];
    const float* e_in = (const float*)d_in[1];
    const int* src = (const int*)d_in[2];
    const int* dst = (const int*)d_in[3];
    const float* fp_w = (const float*)d_in[4];
    const float* fp_b = (const float*)d_in[5];
    const float* ep_w = (const float*)d_in[6];
    const float* ep_b = (const float*)d_in[7];
    const float* A_w = (const float*)d_in[8];
    const float* A_b = (const float*)d_in[9];
    const float* B_w = (const float*)d_in[10];
    const float* B_b = (const float*)d_in[11];
    const float* C_w = (const float*)d_in[12];
    const float* C_b = (const float*)d_in[13];
    const float* D_w = (const float*)d_in[14];
    const float* D_b = (const float*)d_in[15];
    const float* E_w = (const float*)d_in[16];
    const float* E_b = (const float*)d_in[17];
    const float* mlp0_w = (const float*)d_in[18];
    const float* mlp0_b = (const float*)d_in[19];
    const float* mlp1_w = (const float*)d_in[20];
    const float* mlp1_b = (const float*)d_in[21];
    const float* mlp2_w = (const float*)d_in[22];
    const float* mlp2_b = (const float*)d_in[23];
    float* out = (float*)d_out;

    const size_t ND = (size_t)NN * DD;
    const size_t ED = (size_t)NE * DD;
    const size_t FRAG = (size_t)NL * 6 * 3 * 64 * 8;   // u16 count per packed tensor
    char* w = (char*)d_ws;
    float* hbuf = (float*)w; w += ND * 4;
    float* Ahb  = (float*)w; w += ND * 4;
    u16* Bhb = (u16*)w; w += ND * 2;
    u16* Dhb = (u16*)w; w += ND * 2;
    u16* Ehb = (u16*)w; w += ND * 2;
    u16* ebuf = (u16*)w; w += ED * 2;
    int* counts  = (int*)w; w += (size_t)NN * 4;
    int* row_ptr = (int*)w; w += (size_t)(NN + 1) * 4 + 12;
    int* cursor  = (int*)w; w += (size_t)NN * 4;
    int* eperm   = (int*)w; w += (size_t)NE * 4;
    int* srcp    = (int*)w; w += (size_t)NE * 4;
    u16* awf = (u16*)w; w += FRAG * 2;
    u16* bwf = (u16*)w; w += FRAG * 2;
    u16* cwf = (u16*)w; w += FRAG * 2;
    u16* dwf = (u16*)w; w += FRAG * 2;
    u16* ewf = (u16*)w; w += FRAG * 2;
    u16* wfp = (u16*)w; w += (size_t)6 * 64 * 8 * 2;
    u16* wep = (u16*)w; w += (size_t)6 * 64 * 8 * 2;
    size_t need = (size_t)(w - (char*)d_ws);
    if (ws_size < need) return;  // uniform -> graph-safe; fails absmax as diagnostic

    // CSR build (dst-sorted edge permutation) + weight fragment packs
    k_zero_i<<<(NN + 255) / 256, 256, 0, stream>>>(counts, NN);
    k_hist<<<(NE + 255) / 256, 256, 0, stream>>>(dst, counts);
    k_scan<<<1, 1024, 0, stream>>>(counts, row_ptr, cursor, NN);
    k_scatter<<<(NE + 255) / 256, 256, 0, stream>>>(src, dst, cursor, eperm, srcp);
    const int gPack = (NL * 6 * 3 * 64 + 255) / 256;
    k_packCw<<<gPack, 256, 0, stream>>>(A_w, awf);
    k_packCw<<<gPack, 256, 0, stream>>>(B_w, bwf);
    k_packCw<<<gPack, 256, 0, stream>>>(C_w, cwf);
    k_packCw<<<gPack, 256, 0, stream>>>(D_w, dwf);
    k_packCw<<<gPack, 256, 0, stream>>>(E_w, ewf);
    k_packW32<<<2, 256, 0, stream>>>(fp_w, wfp);
    k_packW32<<<2, 256, 0, stream>>>(ep_w, wep);

    // input projections, barrier-free MFMA (edge proj lands in dst-sorted order)
    k_proj_m<false, false><<<256, 256, 0, stream>>>(h_in, wfp, fp_b, hbuf, nullptr, NN / 16);
    k_proj_m<true, true><<<1024, 256, 0, stream>>>(e_in, wep, ep_b, ebuf, eperm, NE / 16);

    const size_t LFRAG = (size_t)6 * 3 * 64 * 8;
    for (int l = 0; l < NL; ++l) {
        const float* Ab = A_b + (size_t)l * DD;
        const float* Bb = B_b + (size_t)l * DD;
        const float* Cb = C_b + (size_t)l * DD;
        const float* Db = D_b + (size_t)l * DD;
        const float* Eb = E_b + (size_t)l * DD;

        k_gemm4m<<<640, 256, 0, stream>>>(hbuf,
                                          awf + l * LFRAG, Ab, bwf + l * LFRAG, Bb,
                                          dwf + l * LFRAG, Db, ewf + l * LFRAG, Eb,
                                          Ahb, Bhb, Dhb, Ehb, NN / 16);
        k_node_edge_w<<<2560, 256, 0, stream>>>(ebuf, cwf + l * LFRAG, Cb, Dhb, Ehb, Bhb,
                                                srcp, row_ptr, Ahb, hbuf);
    }

    // MLP readout: 96 -> 48 (relu) -> 24 (relu) -> 10 (sigmoid). Reuse Ahb as temps.
    float* y1 = Ahb;
    float* y2 = Ahb + (size_t)NN * 48;
    long t0 = (long)NN * 48, t1 = (long)NN * 24, t2 = (long)NN * NCLS;
    k_mlp<<<(int)((t0 + 255) / 256), 256, 0, stream>>>(hbuf, mlp0_w, mlp0_b, y1, DD, 48, 1, t0);
    k_mlp<<<(int)((t1 + 255) / 256), 256, 0, stream>>>(y1, mlp1_w, mlp1_b, y2, 48, 24, 1, t1);
    k_mlp<<<(int)((t2 + 255) / 256), 256, 0, stream>>>(y2, mlp2_w, mlp2_b, out, 24, NCLS, 2, t2);
}

// Round 12
// 1430.444 us; speedup vs baseline: 1.3676x; 1.0316x over previous
//
#include <hip/hip_runtime.h>

#define NN 50000
#define NE 800000
#define DIN 32
#define DD 96
#define NL 4
#define NCLS 10
#define EPSF 1e-6f

typedef unsigned short u16;
typedef unsigned int u32;

typedef __bf16 bf16x8 __attribute__((ext_vector_type(8)));
typedef float f32x4 __attribute__((ext_vector_type(4)));

static __device__ __forceinline__ float bf2f(u16 u) {
    return __uint_as_float(((u32)u) << 16);
}
static __device__ __forceinline__ u16 f2bf(float f) {
    u32 x = __float_as_uint(f);
    x += 0x7FFFu + ((x >> 16) & 1u);   // round-to-nearest-even
    return (u16)(x >> 16);
}
static __device__ __forceinline__ u32 pk2(float a, float b) {
    return (u32)f2bf(a) | ((u32)f2bf(b) << 16);
}
static __device__ __forceinline__ float unlo(u32 u) { return __uint_as_float(u << 16); }
static __device__ __forceinline__ float unhi(u32 u) { return __uint_as_float(u & 0xFFFF0000u); }

__global__ void k_zero_i(int* __restrict__ p, int n) {
    int i = blockIdx.x * blockDim.x + threadIdx.x;
    if (i < n) p[i] = 0;
}

__global__ void k_hist(const int* __restrict__ dst, int* __restrict__ counts) {
    int i = blockIdx.x * blockDim.x + threadIdx.x;
    if (i < NE) atomicAdd(&counts[dst[i]], 1);
}

// single-block exclusive scan over n counts -> row_ptr[0..n], cursor copy.
__global__ __launch_bounds__(1024) void k_scan(const int* __restrict__ counts,
                                               int* __restrict__ row_ptr,
                                               int* __restrict__ cursor, int n) {
    __shared__ int wsum[16];
    __shared__ int carry_s;
    const int tid = threadIdx.x;
    const int lane = tid & 63, wid = tid >> 6;
    if (tid == 0) carry_s = 0;
    __syncthreads();
    for (int base = 0; base < n; base += 1024) {
        int i = base + tid;
        int v = (i < n) ? counts[i] : 0;
        int x = v;
#pragma unroll
        for (int off = 1; off < 64; off <<= 1) {
            int t = __shfl_up(x, (unsigned)off, 64);
            if (lane >= off) x += t;
        }
        if (lane == 63) wsum[wid] = x;
        __syncthreads();
        if (wid == 0 && lane < 16) {
            int s = wsum[lane];
#pragma unroll
            for (int off = 1; off < 16; off <<= 1) {
                int t = __shfl_up(s, (unsigned)off, 16);
                if (lane >= off) s += t;
            }
            wsum[lane] = s;
        }
        __syncthreads();
        int wbase = (wid > 0) ? wsum[wid - 1] : 0;
        int carry = carry_s;
        int excl = carry + wbase + x - v;
        if (i < n) { row_ptr[i] = excl; cursor[i] = excl; }
        __syncthreads();
        if (tid == 0) carry_s = carry + wsum[15];
        __syncthreads();
    }
    if (tid == 0) row_ptr[n] = carry_s;
}

__global__ void k_scatter(const int* __restrict__ src, const int* __restrict__ dst,
                          int* __restrict__ cursor, int* __restrict__ eperm,
                          int* __restrict__ srcp) {
    int i = blockIdx.x * blockDim.x + threadIdx.x;
    if (i >= NE) return;
    int pos = atomicAdd(&cursor[dst[i]], 1);
    eperm[pos] = i;
    srcp[pos] = src[i];
}

// Pack a [NL][96][96] weight tensor into MFMA B-fragment order (bf16).
// kperm!=0: k-axis permuted by pi(k)=(k%6)*16+k/6 (for Cw: e-state stored-pi k).
// Column at (tile,lm) is actual col t*16+lm in all cases.
__global__ void k_packCw(const float* __restrict__ W_all, u16* __restrict__ wf, int kperm) {
    int q = blockIdx.x * blockDim.x + threadIdx.x;   // fragment index
    if (q >= NL * 6 * 3 * 64) return;
    int l = q / (6 * 3 * 64);
    int rem = q - l * (6 * 3 * 64);
    int tile = rem / (3 * 64);
    int rem2 = rem - tile * (3 * 64);
    int c = rem2 >> 6, lane = rem2 & 63;
    const float* W = W_all + (long)l * DD * DD;
    int n = tile * 16 + (lane & 15);
    int k0 = c * 32 + (lane >> 4) * 8;
    u16 w[8];
#pragma unroll
    for (int j = 0; j < 8; ++j) {
        int kk = k0 + j;
        int kact = kperm ? ((kk % 6) * 16 + kk / 6) : kk;
        w[j] = f2bf(W[kact * DD + n]);
    }
    *(uint4*)&wf[(long)q * 8] = *(uint4*)w;
}

// Pack a [32,96] projection W into B-fragment order (6 tiles x 64 lanes x 8)
__global__ void k_packW32(const float* __restrict__ W, u16* __restrict__ wf) {
    int q = blockIdx.x * blockDim.x + threadIdx.x;
    if (q >= 6 * 64) return;
    int tile = q >> 6, lane = q & 63;
    int n = tile * 16 + (lane & 15);
    int k0 = (lane >> 4) * 8;
    u16 w[8];
#pragma unroll
    for (int j = 0; j < 8; ++j) w[j] = f2bf(W[(k0 + j) * DD + n]);
    *(uint4*)&wf[q * 8] = *(uint4*)w;
}

// Barrier-free MFMA input projection: one wave per 16-row tile, grid-stride.
// POUT: store in permuted basis (stored p = lm*6+t holds actual col t*16+lm),
// 3x u32 contiguous stores per row (bf16 only).
template <bool BFOUT, bool PERM, bool POUT>
__global__ __launch_bounds__(256) void k_proj_m(const float* __restrict__ X,
                                                const u16* __restrict__ wf,
                                                const float* __restrict__ B,
                                                void* __restrict__ Y,
                                                const int* __restrict__ eperm,
                                                int ntiles) {
    const int lane = threadIdx.x & 63;
    const int gw = (blockIdx.x * blockDim.x + threadIdx.x) >> 6;
    const int nw = (gridDim.x * blockDim.x) >> 6;
    const int lm = lane & 15, quad = lane >> 4;

    bf16x8 bfr[6];
    float bias[6];
#pragma unroll
    for (int t = 0; t < 6; ++t) {
        bfr[t] = *(const bf16x8*)&wf[(t * 64 + lane) * 8];
        bias[t] = B[t * 16 + lm];
    }

    for (int tile = gw; tile < ntiles; tile += nw) {
        const int row = tile * 16 + lm;
        const long srow = PERM ? (long)eperm[row] : (long)row;
        float4 x0 = *(const float4*)&X[srow * DIN + quad * 8];
        float4 x1 = *(const float4*)&X[srow * DIN + quad * 8 + 4];
        u32 ap[4] = {pk2(x0.x, x0.y), pk2(x0.z, x0.w), pk2(x1.x, x1.y), pk2(x1.z, x1.w)};
        bf16x8 af = *(bf16x8*)ap;
        f32x4 acc[6];
#pragma unroll
        for (int t = 0; t < 6; ++t) {
            acc[t] = (f32x4){0.f, 0.f, 0.f, 0.f};
            acc[t] = __builtin_amdgcn_mfma_f32_16x16x32_bf16(af, bfr[t], acc[t], 0, 0, 0);
        }
        const long rbase = (long)tile * 16 + quad * 4;
        if (POUT) {
#pragma unroll
            for (int r = 0; r < 4; ++r) {
                u16* p = (u16*)Y + (rbase + r) * DD + lm * 6;
                *(u32*)p       = pk2(acc[0][r] + bias[0], acc[1][r] + bias[1]);
                *(u32*)(p + 2) = pk2(acc[2][r] + bias[2], acc[3][r] + bias[3]);
                *(u32*)(p + 4) = pk2(acc[4][r] + bias[4], acc[5][r] + bias[5]);
            }
        } else {
#pragma unroll
            for (int t = 0; t < 6; ++t) {
                const int j = t * 16 + lm;
#pragma unroll
                for (int r = 0; r < 4; ++r) {
                    float v = acc[t][r] + bias[t];
                    if (BFOUT) ((u16*)Y)[(rbase + r) * DD + j] = f2bf(v);
                    else       ((float*)Y)[(rbase + r) * DD + j] = v;
                }
            }
        }
    }
}

// Barrier-free MFMA 4-way node GEMM: wave w of each block handles matrix w.
// Wave 0 (A) -> canonical f32; waves 1-3 (B/D/E) -> bf16 in permuted basis.
__global__ __launch_bounds__(256) void k_gemm4m(const float* __restrict__ X,
                                                const u16* __restrict__ awf, const float* __restrict__ ab,
                                                const u16* __restrict__ bwf, const float* __restrict__ bb,
                                                const u16* __restrict__ dwf, const float* __restrict__ db,
                                                const u16* __restrict__ ewf, const float* __restrict__ eb,
                                                float* __restrict__ Y0, u16* __restrict__ Y1,
                                                u16* __restrict__ Y2, u16* __restrict__ Y3,
                                                int ntiles) {
    const int lane = threadIdx.x & 63;
    const int w = threadIdx.x >> 6;   // matrix 0..3
    const int lm = lane & 15, quad = lane >> 4;
    const u16* wf = (w == 0) ? awf : (w == 1) ? bwf : (w == 2) ? dwf : ewf;
    const float* bp = (w == 0) ? ab : (w == 1) ? bb : (w == 2) ? db : eb;

    bf16x8 bfr[6][3];
    float bias[6];
#pragma unroll
    for (int t = 0; t < 6; ++t) {
#pragma unroll
        for (int c = 0; c < 3; ++c)
            bfr[t][c] = *(const bf16x8*)&wf[((t * 3 + c) * 64 + lane) * 8];
        bias[t] = bp[t * 16 + lm];
    }

    for (int tile = blockIdx.x; tile < ntiles; tile += gridDim.x) {
        const float* xr = X + (long)(tile * 16 + lm) * DD;
        bf16x8 a[3];
#pragma unroll
        for (int c = 0; c < 3; ++c) {
            float4 x0 = *(const float4*)&xr[c * 32 + quad * 8];
            float4 x1 = *(const float4*)&xr[c * 32 + quad * 8 + 4];
            u32 ap[4] = {pk2(x0.x, x0.y), pk2(x0.z, x0.w), pk2(x1.x, x1.y), pk2(x1.z, x1.w)};
            a[c] = *(bf16x8*)ap;
        }
        f32x4 acc[6];
#pragma unroll
        for (int t = 0; t < 6; ++t) {
            acc[t] = (f32x4){0.f, 0.f, 0.f, 0.f};
#pragma unroll
            for (int c = 0; c < 3; ++c)
                acc[t] = __builtin_amdgcn_mfma_f32_16x16x32_bf16(a[c], bfr[t][c], acc[t], 0, 0, 0);
        }
        const long rbase = (long)tile * 16 + quad * 4;
        if (w == 0) {
#pragma unroll
            for (int t = 0; t < 6; ++t) {
                const int j = t * 16 + lm;
#pragma unroll
                for (int r = 0; r < 4; ++r) Y0[(rbase + r) * DD + j] = acc[t][r] + bias[t];
            }
        } else {
            u16* Yp = (w == 1) ? Y1 : (w == 2) ? Y2 : Y3;
#pragma unroll
            for (int r = 0; r < 4; ++r) {
                u16* p = Yp + (rbase + r) * DD + lm * 6;
                *(u32*)p       = pk2(acc[0][r] + bias[0], acc[1][r] + bias[1]);
                *(u32*)(p + 2) = pk2(acc[2][r] + bias[2], acc[3][r] + bias[3]);
                *(u32*)(p + 4) = pk2(acc[4][r] + bias[4], acc[5][r] + bias[5]);
            }
        }
    }
}

// Barrier-free, LDS-free fused edge+aggregate: one wave per node (grid-stride).
// e-state, Bh/Dh/Eh in permuted basis: lane lm owns 6 contiguous u16 per row
// -> all epilogue traffic is 3x u32 per row per tensor.
__global__ __launch_bounds__(256) void k_node_edge_w(u16* ebuf,
                                                     const u16* __restrict__ cwf,  // k-permuted pack
                                                     const float* __restrict__ Cb,
                                                     const u16* __restrict__ Dh,
                                                     const u16* __restrict__ Eh,
                                                     const u16* __restrict__ Bh,
                                                     const int* __restrict__ srcp,
                                                     const int* __restrict__ row_ptr,
                                                     const float* __restrict__ Ah,
                                                     float* __restrict__ hbuf) {
    const int lane = threadIdx.x & 63;
    const int gw = (blockIdx.x * blockDim.x + threadIdx.x) >> 6;
    const int nw = (gridDim.x * blockDim.x) >> 6;
    const int lm = lane & 15, quad = lane >> 4;

    bf16x8 bfrag[6][3];
    float cb[6];
#pragma unroll
    for (int t = 0; t < 6; ++t) {
#pragma unroll
        for (int c = 0; c < 3; ++c)
            bfrag[t][c] = *(const bf16x8*)&cwf[((t * 3 + c) * 64 + lane) * 8];
        cb[t] = Cb[t * 16 + lm];   // stored p=lm*6+t <-> actual col t*16+lm
    }

    for (int n = gw; n < NN; n += nw) {
        const int r0 = row_ptr[n], r1 = row_ptr[n + 1];
        float eh[6];
        {
            const u16* ep = Eh + (long)n * DD + lm * 6;
            u32 e0 = *(const u32*)ep, e1 = *(const u32*)(ep + 2), e2 = *(const u32*)(ep + 4);
            eh[0] = unlo(e0); eh[1] = unhi(e0); eh[2] = unlo(e1);
            eh[3] = unhi(e1); eh[4] = unlo(e2); eh[5] = unhi(e2);
        }
        float nacc[6] = {0.f, 0.f, 0.f, 0.f, 0.f, 0.f};
        float dacc[6] = {0.f, 0.f, 0.f, 0.f, 0.f, 0.f};

        for (int chunk = r0; chunk < r1; chunk += 16) {
            const int rows = r1 - chunk < 16 ? r1 - chunk : 16;
            const long arow = chunk + (lm < rows ? lm : 0);
            bf16x8 a[3];
#pragma unroll
            for (int c = 0; c < 3; ++c)
                a[c] = *(const bf16x8*)&ebuf[arow * DD + c * 32 + quad * 8];
            int sr[4];
#pragma unroll
            for (int r = 0; r < 4; ++r) {
                int rl = quad * 4 + r;
                sr[r] = (chunk + rl < r1) ? srcp[chunk + rl] : 0;
            }
            f32x4 acc[6];
#pragma unroll
            for (int t = 0; t < 6; ++t) {
                acc[t] = (f32x4){0.f, 0.f, 0.f, 0.f};
#pragma unroll
                for (int c = 0; c < 3; ++c)
                    acc[t] = __builtin_amdgcn_mfma_f32_16x16x32_bf16(a[c], bfrag[t][c], acc[t], 0, 0, 0);
            }
            // epilogue: row = quad*4+r; lane owns stored cols lm*6..lm*6+5
#pragma unroll
            for (int r = 0; r < 4; ++r) {
                const int rl = quad * 4 + r;
                if (rl < rows) {
                    const long s = sr[r];
                    const u16* dp = Dh + s * DD + lm * 6;
                    const u16* bp = Bh + s * DD + lm * 6;
                    u16* ep = ebuf + (long)(chunk + rl) * DD + lm * 6;
                    u32 d0 = *(const u32*)dp, d1 = *(const u32*)(dp + 2), d2 = *(const u32*)(dp + 4);
                    u32 b0 = *(const u32*)bp, b1 = *(const u32*)(bp + 2), b2 = *(const u32*)(bp + 4);
                    u32 o0 = *(const u32*)ep, o1 = *(const u32*)(ep + 2), o2 = *(const u32*)(ep + 4);
                    float dh[6] = {unlo(d0), unhi(d0), unlo(d1), unhi(d1), unlo(d2), unhi(d2)};
                    float bh[6] = {unlo(b0), unhi(b0), unlo(b1), unhi(b1), unlo(b2), unhi(b2)};
                    float od[6] = {unlo(o0), unhi(o0), unlo(o1), unhi(o1), unlo(o2), unhi(o2)};
                    float ov[6];
#pragma unroll
                    for (int t = 0; t < 6; ++t) {
                        float en = acc[t][r] + cb[t] + dh[t] + eh[t];
                        float sg = 1.f / (1.f + __expf(-en));
                        nacc[t] += bh[t] * sg;
                        dacc[t] += sg;
                        ov[t] = od[t] + fmaxf(en, 0.f);
                    }
                    *(u32*)ep       = pk2(ov[0], ov[1]);
                    *(u32*)(ep + 2) = pk2(ov[2], ov[3]);
                    *(u32*)(ep + 4) = pk2(ov[4], ov[5]);
                }
            }
        }
        // reduce over quads (butterfly across lane bits 4-5)
#pragma unroll
        for (int t = 0; t < 6; ++t) {
            float x = nacc[t], y = dacc[t];
            x += __shfl_xor(x, 16); y += __shfl_xor(y, 16);
            x += __shfl_xor(x, 32); y += __shfl_xor(y, 32);
            nacc[t] = x; dacc[t] = y;
        }
        if (quad == 0) {
#pragma unroll
            for (int t = 0; t < 6; ++t) {
                const int j = t * 16 + lm;   // actual col of stored p=lm*6+t
                float val = Ah[(long)n * DD + j] + nacc[t] / (dacc[t] + EPSF);
                hbuf[(long)n * DD + j] += fmaxf(val, 0.f);
            }
        }
    }
}

// small MLP stage, one thread per output element
__global__ void k_mlp(const float* __restrict__ X, const float* __restrict__ W,
                      const float* __restrict__ B, float* __restrict__ Y,
                      int K, int Dout, int act, long total) {
    long idx = (long)blockIdx.x * blockDim.x + threadIdx.x;
    if (idx >= total) return;
    int row = (int)(idx / Dout);
    int j = (int)(idx - (long)row * Dout);
    const float* xr = X + (long)row * K;
    float acc = B[j];
    for (int k = 0; k < K; ++k) acc = fmaf(xr[k], W[k * Dout + j], acc);
    if (act == 1) acc = fmaxf(acc, 0.f);
    else if (act == 2) acc = 1.f / (1.f + __expf(-acc));
    Y[idx] = acc;
}

extern "C" void kernel_launch(void* const* d_in, const int* in_sizes, int n_in,
                              void* d_out, int out_size, void* d_ws, size_t ws_size,
                              hipStream_t stream) {
    const float* h_in = (const float*)d_in[0];
    const float* e_in = (const float*)d_in[1];
    const int* src = (const int*)d_in[2];
    const int* dst = (const int*)d_in[3];
    const float* fp_w = (const float*)d_in[4];
    const float* fp_b = (const float*)d_in[5];
    const float* ep_w = (const float*)d_in[6];
    const float* ep_b = (const float*)d_in[7];
    const float* A_w = (const float*)d_in[8];
    const float* A_b = (const float*)d_in[9];
    const float* B_w = (const float*)d_in[10];
    const float* B_b = (const float*)d_in[11];
    const float* C_w = (const float*)d_in[12];
    const float* C_b = (const float*)d_in[13];
    const float* D_w = (const float*)d_in[14];
    const float* D_b = (const float*)d_in[15];
    const float* E_w = (const float*)d_in[16];
    const float* E_b = (const float*)d_in[17];
    const float* mlp0_w = (const float*)d_in[18];
    const float* mlp0_b = (const float*)d_in[19];
    const float* mlp1_w = (const float*)d_in[20];
    const float* mlp1_b = (const float*)d_in[21];
    const float* mlp2_w = (const float*)d_in[22];
    const float* mlp2_b = (const float*)d_in[23];
    float* out = (float*)d_out;

    const size_t ND = (size_t)NN * DD;
    const size_t ED = (size_t)NE * DD;
    const size_t FRAG = (size_t)NL * 6 * 3 * 64 * 8;   // u16 count per packed tensor
    char* w = (char*)d_ws;
    float* hbuf = (float*)w; w += ND * 4;
    float* Ahb  = (float*)w; w += ND * 4;
    u16* Bhb = (u16*)w; w += ND * 2;
    u16* Dhb = (u16*)w; w += ND * 2;
    u16* Ehb = (u16*)w; w += ND * 2;
    u16* ebuf = (u16*)w; w += ED * 2;
    int* counts  = (int*)w; w += (size_t)NN * 4;
    int* row_ptr = (int*)w; w += (size_t)(NN + 1) * 4 + 12;
    int* cursor  = (int*)w; w += (size_t)NN * 4;
    int* eperm   = (int*)w; w += (size_t)NE * 4;
    int* srcp    = (int*)w; w += (size_t)NE * 4;
    u16* awf = (u16*)w; w += FRAG * 2;
    u16* bwf = (u16*)w; w += FRAG * 2;
    u16* cwf = (u16*)w; w += FRAG * 2;
    u16* dwf = (u16*)w; w += FRAG * 2;
    u16* ewf = (u16*)w; w += FRAG * 2;
    u16* wfp = (u16*)w; w += (size_t)6 * 64 * 8 * 2;
    u16* wep = (u16*)w; w += (size_t)6 * 64 * 8 * 2;
    size_t need = (size_t)(w - (char*)d_ws);
    if (ws_size < need) return;  // uniform -> graph-safe; fails absmax as diagnostic

    // CSR build (dst-sorted edge permutation) + weight fragment packs
    k_zero_i<<<(NN + 255) / 256, 256, 0, stream>>>(counts, NN);
    k_hist<<<(NE + 255) / 256, 256, 0, stream>>>(dst, counts);
    k_scan<<<1, 1024, 0, stream>>>(counts, row_ptr, cursor, NN);
    k_scatter<<<(NE + 255) / 256, 256, 0, stream>>>(src, dst, cursor, eperm, srcp);
    const int gPack = (NL * 6 * 3 * 64 + 255) / 256;
    k_packCw<<<gPack, 256, 0, stream>>>(A_w, awf, 0);
    k_packCw<<<gPack, 256, 0, stream>>>(B_w, bwf, 0);
    k_packCw<<<gPack, 256, 0, stream>>>(C_w, cwf, 1);   // k-permuted (e-state basis)
    k_packCw<<<gPack, 256, 0, stream>>>(D_w, dwf, 0);
    k_packCw<<<gPack, 256, 0, stream>>>(E_w, ewf, 0);
    k_packW32<<<2, 256, 0, stream>>>(fp_w, wfp);
    k_packW32<<<2, 256, 0, stream>>>(ep_w, wep);

    // input projections (h canonical f32; e bf16 in permuted basis, dst-sorted)
    k_proj_m<false, false, false><<<256, 256, 0, stream>>>(h_in, wfp, fp_b, hbuf, nullptr, NN / 16);
    k_proj_m<true, true, true><<<1024, 256, 0, stream>>>(e_in, wep, ep_b, ebuf, eperm, NE / 16);

    const size_t LFRAG = (size_t)6 * 3 * 64 * 8;
    for (int l = 0; l < NL; ++l) {
        const float* Ab = A_b + (size_t)l * DD;
        const float* Bb = B_b + (size_t)l * DD;
        const float* Cb = C_b + (size_t)l * DD;
        const float* Db = D_b + (size_t)l * DD;
        const float* Eb = E_b + (size_t)l * DD;

        k_gemm4m<<<640, 256, 0, stream>>>(hbuf,
                                          awf + l * LFRAG, Ab, bwf + l * LFRAG, Bb,
                                          dwf + l * LFRAG, Db, ewf + l * LFRAG, Eb,
                                          Ahb, Bhb, Dhb, Ehb, NN / 16);
        k_node_edge_w<<<2560, 256, 0, stream>>>(ebuf, cwf + l * LFRAG, Cb, Dhb, Ehb, Bhb,
                                                srcp, row_ptr, Ahb, hbuf);
    }

    // MLP readout: 96 -> 48 (relu) -> 24 (relu) -> 10 (sigmoid). Reuse Ahb as temps.
    float* y1 = Ahb;
    float* y2 = Ahb + (size_t)NN * 48;
    long t0 = (long)NN * 48, t1 = (long)NN * 24, t2 = (long)NN * NCLS;
    k_mlp<<<(int)((t0 + 255) / 256), 256, 0, stream>>>(hbuf, mlp0_w, mlp0_b, y1, DD, 48, 1, t0);
    k_mlp<<<(int)((t1 + 255) / 256), 256, 0, stream>>>(y1, mlp1_w, mlp1_b, y2, 48, 24, 1, t1);
    k_mlp<<<(int)((t2 + 255) / 256), 256, 0, stream>>>(y2, mlp2_w, mlp2_b, out, 24, NCLS, 2, t2);
}